// Round 1
// baseline (379.148 us; speedup 1.0000x reference)
//
#include <hip/hip_runtime.h>
#include <math.h>

#define TEMPC   0.07f
#define NBK     15
#define HALFK   7
#define DD      128
#define HHH     256
#define WWW     256
#define PLANE   (HHH * WWW)   // 65536
#define EPSC    1e-8f

// phase-2 decomposition: 60 col-quads (15 rows x 4 float4 quads) x 4 d-chunks of 32
#define NQ      60
#define NCHUNK  4
#define DCH     32
#define NP2     (NQ * NCHUNK)   // 240 active threads in phase 2
#define NPP     240             // padded positions: 15 rows x 16 cols (col 11 duplicated)

// 4-byte-aligned float4: patch rows are only dword-aligned (aw arbitrary).
// gfx9+ global loads support dword-aligned dwordx4.
typedef float f4 __attribute__((ext_vector_type(4), aligned(4)));

__global__ __launch_bounds__(256) void lcl_main(
    const float* __restrict__ feat,
    const int*   __restrict__ targ,
    const int*   __restrict__ anch_h,
    const int*   __restrict__ anch_w,
    float*       __restrict__ loss_part,
    float*       __restrict__ cnt_part)
{
    const int bn   = blockIdx.x;          // b * NUM_SAMPLES + n
    const int b    = bn >> 8;             // NUM_SAMPLES == 256
    const int tid  = threadIdx.x;
    const int lane = tid & 63;
    const int wave = tid >> 6;

    __shared__ float af[DD];
    __shared__ float pd[NCHUNK * NPP];    // dot partials  [c][p]
    __shared__ float pq[NCHUNK * NPP];    // sq partials   [c][p]
    __shared__ float red[4], red2[4], red3[4];
    __shared__ float s_an;
    __shared__ float s_max;

    const int ah = anch_h[bn];
    const int aw = anch_w[bn];
    const int* lab = targ + b * PLANE;
    const int alab = lab[ah * WWW + aw];
    const float* fb = feat + (size_t)b * DD * PLANE;

    // ---- phase 1: stage anchor feature into LDS, reduce its squared norm ----
    float sqa = 0.f;
    if (tid < DD) {
        float v = fb[(size_t)tid * PLANE + ah * WWW + aw];
        af[tid] = v;
        sqa = v * v;
    }
    #pragma unroll
    for (int off = 32; off; off >>= 1) sqa += __shfl_down(sqa, off, 64);
    if (lane == 0) red[wave] = sqa;
    __syncthreads();
    if (tid == 0) s_an = fmaxf(sqrtf(red[0] + red[1] + red[2] + red[3]), EPSC);
    __syncthreads();          // af + s_an ready

    // ---- phase 2: vectorized dot/norm partials ----
    // thread t = c*60 + q : c = d-chunk (32 planes), q = k*4 + ql (row, col-quad).
    // Quad col bases {0,4,8,11}: ql==3 overlaps col 11 so its float4 stays
    // inside the row (cols 11..14); the duplicate (ql==3, j==0) is masked later.
    // Lanes 0..59 of a wave share c -> per iter the wave loads one whole patch
    // plane as 15 rows x 64B contiguous float4s (coalesced), vs 4B scalars before.
    if (tid < NP2) {
        const int c  = tid / NQ;
        const int q  = tid - c * NQ;
        const int k  = q >> 2;
        const int ql = q & 3;
        const int colb = (ql < 3) ? (ql << 2) : 11;
        const int hh = ah - HALFK + k;
        const int ww = aw - HALFK + colb;
        const float* p = fb + (size_t)(c * DCH) * PLANE + (hh * WWW + ww);
        const float* a = &af[c * DCH];     // wave-mostly-uniform -> LDS broadcast
        float d0 = 0.f, d1 = 0.f, d2 = 0.f, d3 = 0.f;
        float s0 = 0.f, s1 = 0.f, s2 = 0.f, s3 = 0.f;
        #pragma unroll 8
        for (int i = 0; i < DCH; ++i) {
            f4 v = *reinterpret_cast<const f4*>(p + i * PLANE);
            float av = a[i];
            d0 = fmaf(av, v[0], d0);  s0 = fmaf(v[0], v[0], s0);
            d1 = fmaf(av, v[1], d1);  s1 = fmaf(v[1], v[1], s1);
            d2 = fmaf(av, v[2], d2);  s2 = fmaf(v[2], v[2], s2);
            d3 = fmaf(av, v[3], d3);  s3 = fmaf(v[3], v[3], s3);
        }
        const int base = c * NPP + (q << 2);   // element index == c*240 + p
        pd[base + 0] = d0; pd[base + 1] = d1; pd[base + 2] = d2; pd[base + 3] = d3;
        pq[base + 0] = s0; pq[base + 1] = s1; pq[base + 2] = s2; pq[base + 3] = s3;
    }
    __syncthreads();

    // ---- phase 3: per-position sim (p = q*4 + j = k*16 + ql*4 + j) ----
    const float an = s_an;
    float sim = -INFINITY;
    bool  pos = false;
    if (tid < NPP) {
        const int ql = (tid >> 2) & 3;
        const int j  = tid & 3;
        if (!(ql == 3 && j == 0)) {            // duplicated col 11 -> masked
            const int k   = tid >> 4;
            const int col = ((ql < 3) ? (ql << 2) : 11) + j;
            // stride-1 LDS reads, conflict-free
            float dot = pd[tid] + pd[NPP + tid] + pd[2 * NPP + tid] + pd[3 * NPP + tid];
            float sq  = pq[tid] + pq[NPP + tid] + pq[2 * NPP + tid] + pq[3 * NPP + tid];
            float pn = fmaxf(sqrtf(sq), EPSC);
            sim = dot / (an * pn * TEMPC);
            const int hh = ah - HALFK + k;
            const int wp = aw - HALFK + col;
            pos = (lab[hh * WWW + wp] == alab) && !(k == HALFK && col == HALFK);
        }
    }

    // ---- phase 3a: block max ----
    float m = sim;
    #pragma unroll
    for (int off = 32; off; off >>= 1) m = fmaxf(m, __shfl_down(m, off, 64));
    if (lane == 0) red[wave] = m;
    __syncthreads();
    if (tid == 0) s_max = fmaxf(fmaxf(red[0], red[1]), fmaxf(red[2], red[3]));
    __syncthreads();
    m = s_max;

    // ---- phase 3b: exp-sum, positive-sum, positive-count ----
    float e  = expf(sim - m);     // sim == -INF (masked/inactive) -> exp == 0
    float ps = pos ? sim : 0.f;
    float pc = pos ? 1.f : 0.f;
    #pragma unroll
    for (int off = 32; off; off >>= 1) {
        e  += __shfl_down(e,  off, 64);
        ps += __shfl_down(ps, off, 64);
        pc += __shfl_down(pc, off, 64);
    }
    if (lane == 0) { red[wave] = e; red2[wave] = ps; red3[wave] = pc; }
    __syncthreads();
    if (tid == 0) {
        float E  = red[0]  + red[1]  + red[2]  + red[3];
        float PS = red2[0] + red2[1] + red2[2] + red2[3];
        float PC = red3[0] + red3[1] + red3[2] + red3[3];
        float lse = m + logf(E);
        bool valid = PC > 0.5f;
        // every block writes its slot unconditionally -> no zero-init of ws needed
        loss_part[bn] = valid ? (lse - PS / PC) : 0.f;
        cnt_part[bn]  = valid ? 1.f : 0.f;
    }
}

__global__ __launch_bounds__(256) void lcl_finalize(
    const float* __restrict__ loss_part,
    const float* __restrict__ cnt_part,
    float*       __restrict__ out,
    int n)
{
    const int tid  = threadIdx.x;
    const int lane = tid & 63;
    const int wave = tid >> 6;
    __shared__ float rs[4], rc[4];

    float s = 0.f, c = 0.f;
    for (int i = tid; i < n; i += 256) {
        s += loss_part[i];
        c += cnt_part[i];
    }
    #pragma unroll
    for (int off = 32; off; off >>= 1) {
        s += __shfl_down(s, off, 64);
        c += __shfl_down(c, off, 64);
    }
    if (lane == 0) { rs[wave] = s; rc[wave] = c; }
    __syncthreads();
    if (tid == 0) {
        float S = rs[0] + rs[1] + rs[2] + rs[3];
        float C = rc[0] + rc[1] + rc[2] + rc[3];
        out[0] = (C > 0.5f) ? (S / C) : 0.f;
    }
}

extern "C" void kernel_launch(void* const* d_in, const int* in_sizes, int n_in,
                              void* d_out, int out_size, void* d_ws, size_t ws_size,
                              hipStream_t stream) {
    const float* feat  = (const float*)d_in[0];
    const int*   targ  = (const int*)d_in[1];
    const int*   anchh = (const int*)d_in[2];
    const int*   anchw = (const int*)d_in[3];
    float* out = (float*)d_out;

    const int n_anchors = in_sizes[2];   // B * NUM_SAMPLES = 2048

    float* loss_part = (float*)d_ws;
    float* cnt_part  = loss_part + n_anchors;

    lcl_main<<<n_anchors, 256, 0, stream>>>(feat, targ, anchh, anchw,
                                            loss_part, cnt_part);
    lcl_finalize<<<1, 256, 0, stream>>>(loss_part, cnt_part, out, n_anchors);
}